// Round 2
// baseline (679.461 us; speedup 1.0000x reference)
//
#include <hip/hip_runtime.h>
#include <hip/hip_bf16.h>

using bf16   = __bf16;
using bf16x4 = __attribute__((ext_vector_type(4))) __bf16;
using bf16x8 = __attribute__((ext_vector_type(8))) __bf16;
using f32x4  = __attribute__((ext_vector_type(4))) float;

#define B_TOT 2048
#define NTOK  98
#define CDIM  192
#define NHEAD 6
#define HDIM  32
#define NWIN  512
#define NN    (NTOK*NTOK)            /* 9604 */
#define QKV_ELEMS ((size_t)B_TOT*NHEAD*NTOK*HDIM)  /* 38535168 */
#define SCALE 0.17677669529663687f   /* 32^-0.5 */

#define MFMA(a,b,c) __builtin_amdgcn_mfma_f32_16x16x32_bf16((a),(b),(c),0,0,0)

// ---------------------------------------------------------------------------
// bias[h][i][j] = rpb_table[rel_pos_index[i*98+j]][h]
// ---------------------------------------------------------------------------
__global__ void build_bias(const float* __restrict__ table,
                           const int* __restrict__ rel,
                           float* __restrict__ bias) {
    int t = blockIdx.x * 256 + threadIdx.x;
    if (t < NN) {
        int idx = rel[t];
        #pragma unroll
        for (int h = 0; h < NHEAD; ++h)
            bias[h * NN + t] = table[idx * NHEAD + h];
    }
}

// f32 -> bf16 weight conversion (run into dead ws regions)
__global__ void wconv(const float* __restrict__ w, bf16* __restrict__ wb, int n) {
    int t = blockIdx.x * 256 + threadIdx.x;
    if (t < n) wb[t] = (bf16)w[t];
}

// ---------------------------------------------------------------------------
// QKV GEMM v2. BM=128, K=192 (all in LDS as bf16, A-fragments hoisted to
// registers), B read directly from preconverted bf16 W (L1-hot, 24KB/chunk).
// One barrier per block. Wave owns 32 rows x all 576 cols.
// Stores q*scale, k, v all as [b][h][n][hd] bf16.
// ---------------------------------------------------------------------------
__global__ __launch_bounds__(256, 2) void qkv_gemm(
    const float* __restrict__ x, const bf16* __restrict__ wb,
    const float* __restrict__ bvec,
    bf16* __restrict__ qdst, bf16* __restrict__ kdst, bf16* __restrict__ vdst)
{
    __shared__ char As[49152];   // 128 rows * 384 B (192 bf16), swizzled
    const int tid = threadIdx.x;
    const int m0  = blockIdx.x * 128;

    for (int c = tid; c < 128 * 48; c += 256) {
        int row = c / 48, c4 = c % 48;
        const float4 v = *(const float4*)(x + (size_t)(m0 + row) * CDIM + c4 * 4);
        bf16x4 p; p[0] = (bf16)v.x; p[1] = (bf16)v.y; p[2] = (bf16)v.z; p[3] = (bf16)v.w;
        *(bf16x4*)(As + row * 384 + ((((c4 >> 1) ^ (row & 7)) << 4) | ((c4 & 1) << 3))) = p;
    }
    __syncthreads();

    const int lane = tid & 63, wave = tid >> 6;
    const int l15 = lane & 15, l16 = lane >> 4;

    // hoist A fragments (wave owns rows [wave*32, wave*32+32))
    bf16x8 af[2][6];
    #pragma unroll
    for (int it = 0; it < 2; ++it) {
        int row = wave * 32 + it * 16 + l15;
        #pragma unroll
        for (int ks = 0; ks < 6; ++ks) {
            int kchunk = ks * 4 + l16;
            af[it][ks] = *(const bf16x8*)(As + row * 384 + ((kchunk ^ (row & 7)) << 4));
        }
    }

    // precompute output row offsets: b*6*98*32 + n*32
    int offA[2][4];
    #pragma unroll
    for (int it = 0; it < 2; ++it) {
        int rowb = m0 + wave * 32 + it * 16 + l16 * 4;
        int b0 = rowb / NTOK, n0 = rowb % NTOK;
        #pragma unroll
        for (int r = 0; r < 4; ++r) {
            int b = b0, n = n0 + r;
            if (n >= NTOK) { b += 1; n -= NTOK; }
            offA[it][r] = b * 18816 + n * 32;
        }
    }

    const f32x4 z4 = {0.f, 0.f, 0.f, 0.f};
    #pragma unroll
    for (int nc = 0; nc < 9; ++nc) {
        f32x4 acc[2][4];
        #pragma unroll
        for (int it = 0; it < 2; ++it)
            #pragma unroll
            for (int ct = 0; ct < 4; ++ct) acc[it][ct] = z4;

        #pragma unroll
        for (int ks = 0; ks < 6; ++ks) {
            int kchunk = ks * 4 + l16;
            #pragma unroll
            for (int ct = 0; ct < 4; ++ct) {
                int brow = nc * 64 + ct * 16 + l15;
                bf16x8 bfr = *(const bf16x8*)(wb + (size_t)brow * CDIM + kchunk * 8);
                acc[0][ct] = MFMA(af[0][ks], bfr, acc[0][ct]);
                acc[1][ct] = MFMA(af[1][ks], bfr, acc[1][ct]);
            }
        }

        #pragma unroll
        for (int ct = 0; ct < 4; ++ct) {
            const int base  = nc * 64 + ct * 16;   // compile-time after unroll
            const int which = base / CDIM;
            const int hh    = (base % CDIM) >> 5;
            const int hd0   = (base & 31);
            const float bv  = bvec[base + l15];
            const int hoff  = hh * 3136 + hd0 + l15;
            #pragma unroll
            for (int it = 0; it < 2; ++it) {
                #pragma unroll
                for (int r = 0; r < 4; ++r) {
                    float v = acc[it][ct][r] + bv;
                    size_t a = (size_t)(offA[it][r] + hoff);
                    if (which == 0)      qdst[a] = (bf16)(v * SCALE);
                    else if (which == 1) kdst[a] = (bf16)v;
                    else                 vdst[a] = (bf16)v;
                }
            }
        }
    }
}

// ---------------------------------------------------------------------------
// Fused attention v2: one block per WINDOW, 7 waves, loops 6 heads.
// Mask held in registers across heads (6x fewer L3 mask reads).
// V transposed into LDS at staging time. Softmax in-place on acc.
// ---------------------------------------------------------------------------
__global__ __launch_bounds__(448) void attn_fused(
    const bf16* __restrict__ q, const bf16* __restrict__ k,
    const bf16* __restrict__ v,
    const float* __restrict__ mask, const float* __restrict__ bias,
    bf16* __restrict__ ao)
{
    __shared__ char lds[8192 + 28672];
    char* Vt = lds;           // 32 x 128 bf16, 256B rows, swizzled
    char* P  = lds + 8192;    // 112 x 128 bf16, 256B rows, swizzled

    const int b = blockIdx.x;
    const int w = b & (NWIN - 1);
    const int tid = threadIdx.x, lane = tid & 63, it = tid >> 6;
    const int l15 = lane & 15, l16 = lane >> 4;

    // one-time zero of Vt pad cols 98..127 and P pad cols 112..127
    for (int f = tid; f < 32 * 30; f += 448) {
        int hd = f / 30, n = 98 + f % 30;
        *(bf16*)(Vt + hd * 256 + (((n >> 3) ^ (hd & 7)) << 4) + ((n & 7) << 1)) = (bf16)0.f;
    }
    {
        int zr = it * 16 + l15;
        int zc = 112 + l16 * 4;
        *(unsigned long long*)(P + zr * 256 + (((zc >> 3) ^ (zr & 7)) << 4) + ((zc & 7) << 1)) = 0ull;
    }

    // mask into registers (reused by all 6 heads)
    const float* mrow = mask + (size_t)w * NN;
    int irow[4];
    float mreg[7][4];
    #pragma unroll
    for (int r = 0; r < 4; ++r) {
        int i = it * 16 + l16 * 4 + r; if (i > 97) i = 97;
        irow[r] = i;
        #pragma unroll
        for (int jt = 0; jt < 7; ++jt) {
            int j = jt * 16 + l15;
            mreg[jt][r] = (j < NTOK) ? mrow[i * NTOK + j] : 0.f;
        }
    }

    int qrow = it * 16 + l15; if (qrow > 97) qrow = 97;
    const f32x4 z4 = {0.f, 0.f, 0.f, 0.f};

    for (int h = 0; h < NHEAD; ++h) {
        const size_t bh = (size_t)b * NHEAD + h;
        // stage V^T (transpose in LDS): coalesced bf16x8 global reads
        if (tid < 392) {
            int n = tid >> 2, hd0 = (tid & 3) * 8;
            bf16x8 vv = *(const bf16x8*)(v + bh * 3136 + n * 32 + hd0);
            #pragma unroll
            for (int e = 0; e < 8; ++e) {
                int hd = hd0 + e;
                *(bf16*)(Vt + hd * 256 + (((n >> 3) ^ (hd & 7)) << 4) + ((n & 7) << 1)) = vv[e];
            }
        }

        // QK^T
        const bf16* qsrc = q + bh * 3136;
        const bf16* ksrc = k + bh * 3136;
        const bf16x8 qf = *(const bf16x8*)(qsrc + qrow * HDIM + l16 * 8);
        f32x4 acc[7];
        #pragma unroll
        for (int jt = 0; jt < 7; ++jt) {
            int kr = jt * 16 + l15; if (kr > 97) kr = 97;
            bf16x8 kf = *(const bf16x8*)(ksrc + kr * HDIM + l16 * 8);
            acc[jt] = MFMA(qf, kf, z4);
        }

        // bias + mask + softmax, in place on acc
        const float* brow = bias + (size_t)h * NN;
        #pragma unroll
        for (int r = 0; r < 4; ++r) {
            #pragma unroll
            for (int jt = 0; jt < 7; ++jt) {
                int j = jt * 16 + l15;
                acc[jt][r] = (j < NTOK)
                    ? (acc[jt][r] + mreg[jt][r] + brow[irow[r] * NTOK + j])
                    : -__builtin_inff();
            }
            float m = acc[0][r];
            #pragma unroll
            for (int jt = 1; jt < 7; ++jt) m = fmaxf(m, acc[jt][r]);
            m = fmaxf(m, __shfl_xor(m, 1, 16));
            m = fmaxf(m, __shfl_xor(m, 2, 16));
            m = fmaxf(m, __shfl_xor(m, 4, 16));
            m = fmaxf(m, __shfl_xor(m, 8, 16));
            float s = 0.f;
            #pragma unroll
            for (int jt = 0; jt < 7; ++jt) {
                float e = __expf(acc[jt][r] - m);
                acc[jt][r] = e; s += e;
            }
            s += __shfl_xor(s, 1, 16);
            s += __shfl_xor(s, 2, 16);
            s += __shfl_xor(s, 4, 16);
            s += __shfl_xor(s, 8, 16);
            float inv = 1.f / s;
            #pragma unroll
            for (int jt = 0; jt < 7; ++jt) acc[jt][r] *= inv;
        }

        // write P (own wave's rows only — no sync needed for P)
        #pragma unroll
        for (int jt = 0; jt < 7; ++jt) {
            #pragma unroll
            for (int r = 0; r < 4; ++r) {
                int row = it * 16 + l16 * 4 + r;
                int j = jt * 16 + l15;
                *(bf16*)(P + row * 256 + (((j >> 3) ^ (row & 7)) << 4) + ((j & 7) << 1))
                    = (bf16)acc[jt][r];
            }
        }
        __syncthreads();   // Vt staged by all threads

        // PV
        f32x4 o0 = z4, o1 = z4;
        const int prow = it * 16 + l15;
        #pragma unroll
        for (int ks = 0; ks < 4; ++ks) {
            int kchunk = ks * 4 + l16;
            bf16x8 pf = *(const bf16x8*)(P + prow * 256 + ((kchunk ^ (prow & 7)) << 4));
            bf16x8 v0 = *(const bf16x8*)(Vt + l15 * 256 + ((kchunk ^ (l15 & 7)) << 4));
            bf16x8 v1 = *(const bf16x8*)(Vt + (16 + l15) * 256 + ((kchunk ^ (l15 & 7)) << 4));
            o0 = MFMA(pf, v0, o0);
            o1 = MFMA(pf, v1, o1);
        }

        bf16* dst = ao + (size_t)b * NTOK * CDIM + h * HDIM;
        #pragma unroll
        for (int r = 0; r < 4; ++r) {
            int row = it * 16 + l16 * 4 + r;
            if (row < NTOK) {
                dst[(size_t)row * CDIM + l15]      = (bf16)o0[r];
                dst[(size_t)row * CDIM + 16 + l15] = (bf16)o1[r];
            }
        }
        __syncthreads();   // protect Vt before next head's staging
    }
}

// ---------------------------------------------------------------------------
// Proj GEMM v2: same structure as qkv_gemm (A hoisted, B from bf16 global).
// ---------------------------------------------------------------------------
__global__ __launch_bounds__(256, 2) void proj_gemm(
    const bf16* __restrict__ ao, const bf16* __restrict__ wb,
    const float* __restrict__ bvec, float* __restrict__ out)
{
    __shared__ char As[49152];
    const int tid = threadIdx.x;
    const int m0  = blockIdx.x * 128;

    for (int c = tid; c < 128 * 24; c += 256) {
        int row = c / 24, c8 = c % 24;
        bf16x8 vv = *(const bf16x8*)(ao + (size_t)(m0 + row) * CDIM + c8 * 8);
        *(bf16x8*)(As + row * 384 + ((c8 ^ (row & 7)) << 4)) = vv;
    }
    __syncthreads();

    const int lane = tid & 63, wave = tid >> 6;
    const int l15 = lane & 15, l16 = lane >> 4;

    bf16x8 af[2][6];
    #pragma unroll
    for (int it = 0; it < 2; ++it) {
        int row = wave * 32 + it * 16 + l15;
        #pragma unroll
        for (int ks = 0; ks < 6; ++ks) {
            int kchunk = ks * 4 + l16;
            af[it][ks] = *(const bf16x8*)(As + row * 384 + ((kchunk ^ (row & 7)) << 4));
        }
    }

    const f32x4 z4 = {0.f, 0.f, 0.f, 0.f};
    #pragma unroll
    for (int nc = 0; nc < 3; ++nc) {
        f32x4 acc[2][4];
        #pragma unroll
        for (int it = 0; it < 2; ++it)
            #pragma unroll
            for (int ct = 0; ct < 4; ++ct) acc[it][ct] = z4;

        #pragma unroll
        for (int ks = 0; ks < 6; ++ks) {
            int kchunk = ks * 4 + l16;
            #pragma unroll
            for (int ct = 0; ct < 4; ++ct) {
                int brow = nc * 64 + ct * 16 + l15;
                bf16x8 bfr = *(const bf16x8*)(wb + (size_t)brow * CDIM + kchunk * 8);
                acc[0][ct] = MFMA(af[0][ks], bfr, acc[0][ct]);
                acc[1][ct] = MFMA(af[1][ks], bfr, acc[1][ct]);
            }
        }

        #pragma unroll
        for (int ct = 0; ct < 4; ++ct) {
            int col = nc * 64 + ct * 16 + l15;
            float bv = bvec[col];
            #pragma unroll
            for (int it = 0; it < 2; ++it) {
                #pragma unroll
                for (int r = 0; r < 4; ++r) {
                    int row = m0 + wave * 32 + it * 16 + l16 * 4 + r;
                    out[(size_t)row * CDIM + col] = acc[it][ct][r] + bv;
                }
            }
        }
    }
}

// ---------------------------------------------------------------------------
extern "C" void kernel_launch(void* const* d_in, const int* in_sizes, int n_in,
                              void* d_out, int out_size, void* d_ws, size_t ws_size,
                              hipStream_t stream)
{
    (void)in_sizes; (void)n_in; (void)out_size; (void)ws_size;
    const float* x      = (const float*)d_in[0];
    const float* mask   = (const float*)d_in[1];
    const float* qkv_w  = (const float*)d_in[2];
    const float* qkv_b  = (const float*)d_in[3];
    const float* proj_w = (const float*)d_in[4];
    const float* proj_b = (const float*)d_in[5];
    const float* rpb    = (const float*)d_in[6];
    const int*   rel    = (const int*)d_in[7];
    float* out = (float*)d_out;

    char* ws = (char*)d_ws;
    bf16* qb = (bf16*)ws;
    bf16* kb = qb + QKV_ELEMS;
    bf16* vb = kb + QKV_ELEMS;
    size_t off = 3 * QKV_ELEMS * sizeof(bf16);          // 231,211,008
    float* bias = (float*)(ws + off);
    off += ((size_t)NHEAD * NN * 4 + 255) / 256 * 256;
    bf16* ao = (bf16*)(ws + off);                        // 77,070,336 B
    // overlapped weight buffers (exact same ws footprint as round 0):
    bf16* qwb = ao;            // live only until qkv_gemm; attn rewrites ao after
    bf16* pwb = qb;            // written after attn (qb dead), read by proj

    build_bias<<<(NN + 255) / 256, 256, 0, stream>>>(rpb, rel, bias);
    wconv<<<(3 * CDIM * CDIM + 255) / 256, 256, 0, stream>>>(qkv_w, qwb, 3 * CDIM * CDIM);
    qkv_gemm<<<200704 / 128, 256, 0, stream>>>(x, qwb, qkv_b, qb, kb, vb);
    attn_fused<<<B_TOT, 448, 0, stream>>>(qb, kb, vb, mask, bias, ao);
    wconv<<<(CDIM * CDIM + 255) / 256, 256, 0, stream>>>(proj_w, pwb, CDIM * CDIM);
    proj_gemm<<<200704 / 128, 256, 0, stream>>>(ao, pwb, proj_b, out);
}

// Round 3
// 565.072 us; speedup vs baseline: 1.2024x; 1.2024x over previous
//
#include <hip/hip_runtime.h>
#include <hip/hip_bf16.h>

using bf16   = __bf16;
using bf16x4 = __attribute__((ext_vector_type(4))) __bf16;
using bf16x8 = __attribute__((ext_vector_type(8))) __bf16;
using f32x4  = __attribute__((ext_vector_type(4))) float;

#define B_TOT 2048
#define NTOK  98
#define CDIM  192
#define NHEAD 6
#define HDIM  32
#define NWIN  512
#define NN    (NTOK*NTOK)            /* 9604 */
#define QKV_ELEMS ((size_t)B_TOT*NHEAD*NTOK*HDIM)  /* 38535168 */
#define SCALE 0.17677669529663687f   /* 32^-0.5 */

#define MFMA(a,b,c) __builtin_amdgcn_mfma_f32_16x16x32_bf16((a),(b),(c),0,0,0)

// ---------------------------------------------------------------------------
// bias[h][i][j] = rpb_table[rel_pos_index[i*98+j]][h]
// ---------------------------------------------------------------------------
__global__ void build_bias(const float* __restrict__ table,
                           const int* __restrict__ rel,
                           float* __restrict__ bias) {
    int t = blockIdx.x * 256 + threadIdx.x;
    if (t < NN) {
        int idx = rel[t];
        #pragma unroll
        for (int h = 0; h < NHEAD; ++h)
            bias[h * NN + t] = table[idx * NHEAD + h];
    }
}

// f32 -> bf16 weight conversion (into dead ws regions)
__global__ void wconv(const float* __restrict__ w, bf16* __restrict__ wb, int n) {
    int t = blockIdx.x * 256 + threadIdx.x;
    if (t < n) wb[t] = (bf16)w[t];
}

// ---------------------------------------------------------------------------
// QKV GEMM v3. BM=64, 128 threads (2 waves x 32 rows). A staged once in LDS
// (swizzled) then hoisted to registers; B-fragments from global bf16 W with a
// one-step register double-buffer (flattened 54-step K/chunk loop) so loads
// for step t+1 are in flight during step t's MFMAs. MFMA operands SWAPPED so
// each lane holds 4 consecutive output cols -> direct bf16x4 stores.
// launch_bounds(128,3): 6 blocks/CU (24KB LDS) = 3 waves/SIMD.
// ---------------------------------------------------------------------------
__global__ __launch_bounds__(128, 3) void qkv_gemm(
    const float* __restrict__ x, const bf16* __restrict__ wb,
    const float* __restrict__ bvec,
    bf16* __restrict__ qdst, bf16* __restrict__ kdst, bf16* __restrict__ vdst)
{
    __shared__ char As[24576];   // 64 rows * 384 B (192 bf16), swizzled
    const int tid = threadIdx.x;
    const int m0  = blockIdx.x * 64;

    for (int c = tid; c < 64 * 48; c += 128) {
        int row = c / 48, c4 = c % 48;
        const float4 v = *(const float4*)(x + (size_t)(m0 + row) * CDIM + c4 * 4);
        bf16x4 p; p[0] = (bf16)v.x; p[1] = (bf16)v.y; p[2] = (bf16)v.z; p[3] = (bf16)v.w;
        *(bf16x4*)(As + row * 384 + ((((c4 >> 1) ^ (row & 7)) << 4) | ((c4 & 1) << 3))) = p;
    }
    __syncthreads();

    const int lane = tid & 63, wave = tid >> 6;
    const int l15 = lane & 15, l16 = lane >> 4;

    // hoist A fragments (wave owns rows [wave*32, wave*32+32))
    bf16x8 af[2][6];
    #pragma unroll
    for (int it = 0; it < 2; ++it) {
        int row = wave * 32 + it * 16 + l15;
        #pragma unroll
        for (int ks = 0; ks < 6; ++ks) {
            int kchunk = ks * 4 + l16;
            af[it][ks] = *(const bf16x8*)(As + row * 384 + ((kchunk ^ (row & 7)) << 4));
        }
    }

    // output row offsets (row = ... + l15 after operand swap)
    int rowoff[2];
    #pragma unroll
    for (int it = 0; it < 2; ++it) {
        int row = m0 + wave * 32 + it * 16 + l15;
        rowoff[it] = (row / NTOK) * 18816 + (row % NTOK) * 32;
    }

    const bf16* wlane = wb + (size_t)l15 * CDIM + l16 * 8;

    const f32x4 z4 = {0.f, 0.f, 0.f, 0.f};
    f32x4 acc[2][4];
    bf16x8 bcur[4], bnxt[4];
    #pragma unroll
    for (int ct = 0; ct < 4; ++ct)
        bcur[ct] = *(const bf16x8*)(wlane + (size_t)(ct * 16) * CDIM);

    #pragma unroll
    for (int t = 0; t < 54; ++t) {
        const int nc = t / 6, ks = t % 6;
        if (ks == 0) {
            #pragma unroll
            for (int it = 0; it < 2; ++it)
                #pragma unroll
                for (int ct = 0; ct < 4; ++ct) acc[it][ct] = z4;
        }
        if (t < 53) {   // prefetch next step's B fragments
            const int nn = (t + 1) / 6, kk = (t + 1) % 6;
            #pragma unroll
            for (int ct = 0; ct < 4; ++ct)
                bnxt[ct] = *(const bf16x8*)(wlane + (size_t)(nn * 64 + ct * 16) * CDIM + kk * 32);
        }
        #pragma unroll
        for (int ct = 0; ct < 4; ++ct) {
            acc[0][ct] = MFMA(bcur[ct], af[0][ks], acc[0][ct]);
            acc[1][ct] = MFMA(bcur[ct], af[1][ks], acc[1][ct]);
        }
        if (t < 53) {
            #pragma unroll
            for (int ct = 0; ct < 4; ++ct) bcur[ct] = bnxt[ct];
        }
        if (ks == 5) {  // epilogue for chunk nc: lane holds rows=l15, cols l16*4+r
            #pragma unroll
            for (int ct = 0; ct < 4; ++ct) {
                const int g0    = nc * 64 + ct * 16;   // compile-time
                const int which = g0 / CDIM;
                const int cm    = g0 % CDIM;
                const int h     = cm >> 5, hd0 = cm & 31;
                const float4 bvf = *(const float4*)(bvec + g0 + l16 * 4);
                #pragma unroll
                for (int it = 0; it < 2; ++it) {
                    bf16x4 s;
                    #pragma unroll
                    for (int r = 0; r < 4; ++r) {
                        float v = acc[it][ct][r] + ((const float*)&bvf)[r];
                        if (which == 0) v *= SCALE;
                        s[r] = (bf16)v;
                    }
                    bf16* dp = (which == 0) ? qdst : (which == 1) ? kdst : vdst;
                    *(bf16x4*)(dp + rowoff[it] + h * 3136 + hd0 + l16 * 4) = s;
                }
            }
        }
    }
}

// ---------------------------------------------------------------------------
// Fused attention: one block per WINDOW, 7 waves, loops 6 heads.
// Mask in registers across heads. PV MFMA operand-swapped -> bf16x4 stores.
// ---------------------------------------------------------------------------
__global__ __launch_bounds__(448) void attn_fused(
    const bf16* __restrict__ q, const bf16* __restrict__ k,
    const bf16* __restrict__ v,
    const float* __restrict__ mask, const float* __restrict__ bias,
    bf16* __restrict__ ao)
{
    __shared__ char lds[8192 + 28672];
    char* Vt = lds;           // 32 x 128 bf16, 256B rows, swizzled
    char* P  = lds + 8192;    // 112 x 128 bf16, 256B rows, swizzled

    const int b = blockIdx.x;
    const int w = b & (NWIN - 1);
    const int tid = threadIdx.x, lane = tid & 63, it = tid >> 6;
    const int l15 = lane & 15, l16 = lane >> 4;

    // one-time zero of Vt pad cols 98..127 and P pad cols 112..127
    for (int f = tid; f < 32 * 30; f += 448) {
        int hd = f / 30, n = 98 + f % 30;
        *(bf16*)(Vt + hd * 256 + (((n >> 3) ^ (hd & 7)) << 4) + ((n & 7) << 1)) = (bf16)0.f;
    }
    {
        int zr = it * 16 + l15;
        int zc = 112 + l16 * 4;
        *(unsigned long long*)(P + zr * 256 + (((zc >> 3) ^ (zr & 7)) << 4) + ((zc & 7) << 1)) = 0ull;
    }

    // mask into registers (reused by all 6 heads)
    const float* mrow = mask + (size_t)w * NN;
    int irow[4];
    float mreg[7][4];
    #pragma unroll
    for (int r = 0; r < 4; ++r) {
        int i = it * 16 + l16 * 4 + r; if (i > 97) i = 97;
        irow[r] = i;
        #pragma unroll
        for (int jt = 0; jt < 7; ++jt) {
            int j = jt * 16 + l15;
            mreg[jt][r] = (j < NTOK) ? mrow[i * NTOK + j] : 0.f;
        }
    }

    int qrow = it * 16 + l15; if (qrow > 97) qrow = 97;
    const f32x4 z4 = {0.f, 0.f, 0.f, 0.f};

    for (int h = 0; h < NHEAD; ++h) {
        const size_t bh = (size_t)b * NHEAD + h;
        // stage V^T (transpose in LDS)
        if (tid < 392) {
            int n = tid >> 2, hd0 = (tid & 3) * 8;
            bf16x8 vv = *(const bf16x8*)(v + bh * 3136 + n * 32 + hd0);
            #pragma unroll
            for (int e = 0; e < 8; ++e) {
                int hd = hd0 + e;
                *(bf16*)(Vt + hd * 256 + (((n >> 3) ^ (hd & 7)) << 4) + ((n & 7) << 1)) = vv[e];
            }
        }

        // QK^T
        const bf16* qsrc = q + bh * 3136;
        const bf16* ksrc = k + bh * 3136;
        const bf16x8 qf = *(const bf16x8*)(qsrc + qrow * HDIM + l16 * 8);
        f32x4 acc[7];
        #pragma unroll
        for (int jt = 0; jt < 7; ++jt) {
            int kr = jt * 16 + l15; if (kr > 97) kr = 97;
            bf16x8 kf = *(const bf16x8*)(ksrc + kr * HDIM + l16 * 8);
            acc[jt] = MFMA(qf, kf, z4);
        }

        // bias + mask + softmax, in place on acc
        const float* brow = bias + (size_t)h * NN;
        #pragma unroll
        for (int r = 0; r < 4; ++r) {
            #pragma unroll
            for (int jt = 0; jt < 7; ++jt) {
                int j = jt * 16 + l15;
                acc[jt][r] = (j < NTOK)
                    ? (acc[jt][r] + mreg[jt][r] + brow[irow[r] * NTOK + j])
                    : -__builtin_inff();
            }
            float m = acc[0][r];
            #pragma unroll
            for (int jt = 1; jt < 7; ++jt) m = fmaxf(m, acc[jt][r]);
            m = fmaxf(m, __shfl_xor(m, 1, 16));
            m = fmaxf(m, __shfl_xor(m, 2, 16));
            m = fmaxf(m, __shfl_xor(m, 4, 16));
            m = fmaxf(m, __shfl_xor(m, 8, 16));
            float s = 0.f;
            #pragma unroll
            for (int jt = 0; jt < 7; ++jt) {
                float e = __expf(acc[jt][r] - m);
                acc[jt][r] = e; s += e;
            }
            s += __shfl_xor(s, 1, 16);
            s += __shfl_xor(s, 2, 16);
            s += __shfl_xor(s, 4, 16);
            s += __shfl_xor(s, 8, 16);
            float inv = 1.f / s;
            #pragma unroll
            for (int jt = 0; jt < 7; ++jt) acc[jt][r] *= inv;
        }

        // write P (own wave's rows only)
        #pragma unroll
        for (int jt = 0; jt < 7; ++jt) {
            #pragma unroll
            for (int r = 0; r < 4; ++r) {
                int row = it * 16 + l16 * 4 + r;
                int j = jt * 16 + l15;
                *(bf16*)(P + row * 256 + (((j >> 3) ^ (row & 7)) << 4) + ((j & 7) << 1))
                    = (bf16)acc[jt][r];
            }
        }
        __syncthreads();   // Vt staged by all threads

        // PV, operands swapped: lane holds row=it*16+l15, cols hd=l16*4+r (+16)
        f32x4 o0 = z4, o1 = z4;
        const int prow = it * 16 + l15;
        #pragma unroll
        for (int ks = 0; ks < 4; ++ks) {
            int kchunk = ks * 4 + l16;
            bf16x8 pf = *(const bf16x8*)(P + prow * 256 + ((kchunk ^ (prow & 7)) << 4));
            bf16x8 v0 = *(const bf16x8*)(Vt + l15 * 256 + ((kchunk ^ (l15 & 7)) << 4));
            bf16x8 v1 = *(const bf16x8*)(Vt + (16 + l15) * 256 + ((kchunk ^ (l15 & 7)) << 4));
            o0 = MFMA(v0, pf, o0);
            o1 = MFMA(v1, pf, o1);
        }

        bf16* dst = ao + (size_t)b * NTOK * CDIM + h * HDIM;
        {
            int row = it * 16 + l15;
            if (row < NTOK) {
                bf16x4 s0, s1;
                #pragma unroll
                for (int r = 0; r < 4; ++r) { s0[r] = (bf16)o0[r]; s1[r] = (bf16)o1[r]; }
                *(bf16x4*)(dst + (size_t)row * CDIM + l16 * 4)      = s0;
                *(bf16x4*)(dst + (size_t)row * CDIM + 16 + l16 * 4) = s1;
            }
        }
        __syncthreads();   // protect Vt/P before next head
    }
}

// ---------------------------------------------------------------------------
// Proj GEMM v3: same structure as qkv_gemm v3. Output f32, f32x4 stores
// (fully line-coalesced after operand swap).
// ---------------------------------------------------------------------------
__global__ __launch_bounds__(128, 3) void proj_gemm(
    const bf16* __restrict__ ao, const bf16* __restrict__ wb,
    const float* __restrict__ bvec, float* __restrict__ out)
{
    __shared__ char As[24576];
    const int tid = threadIdx.x;
    const int m0  = blockIdx.x * 64;

    for (int c = tid; c < 64 * 24; c += 128) {
        int row = c / 24, c8 = c % 24;
        bf16x8 vv = *(const bf16x8*)(ao + (size_t)(m0 + row) * CDIM + c8 * 8);
        *(bf16x8*)(As + row * 384 + ((c8 ^ (row & 7)) << 4)) = vv;
    }
    __syncthreads();

    const int lane = tid & 63, wave = tid >> 6;
    const int l15 = lane & 15, l16 = lane >> 4;

    bf16x8 af[2][6];
    #pragma unroll
    for (int it = 0; it < 2; ++it) {
        int row = wave * 32 + it * 16 + l15;
        #pragma unroll
        for (int ks = 0; ks < 6; ++ks) {
            int kchunk = ks * 4 + l16;
            af[it][ks] = *(const bf16x8*)(As + row * 384 + ((kchunk ^ (row & 7)) << 4));
        }
    }

    int orow[2];
    #pragma unroll
    for (int it = 0; it < 2; ++it)
        orow[it] = (m0 + wave * 32 + it * 16 + l15) * CDIM;

    const bf16* wlane = wb + (size_t)l15 * CDIM + l16 * 8;

    const f32x4 z4 = {0.f, 0.f, 0.f, 0.f};
    f32x4 acc[2][4];
    bf16x8 bcur[4], bnxt[4];
    #pragma unroll
    for (int ct = 0; ct < 4; ++ct)
        bcur[ct] = *(const bf16x8*)(wlane + (size_t)(ct * 16) * CDIM);

    #pragma unroll
    for (int t = 0; t < 18; ++t) {
        const int nc = t / 6, ks = t % 6;
        if (ks == 0) {
            #pragma unroll
            for (int it = 0; it < 2; ++it)
                #pragma unroll
                for (int ct = 0; ct < 4; ++ct) acc[it][ct] = z4;
        }
        if (t < 17) {
            const int nn = (t + 1) / 6, kk = (t + 1) % 6;
            #pragma unroll
            for (int ct = 0; ct < 4; ++ct)
                bnxt[ct] = *(const bf16x8*)(wlane + (size_t)(nn * 64 + ct * 16) * CDIM + kk * 32);
        }
        #pragma unroll
        for (int ct = 0; ct < 4; ++ct) {
            acc[0][ct] = MFMA(bcur[ct], af[0][ks], acc[0][ct]);
            acc[1][ct] = MFMA(bcur[ct], af[1][ks], acc[1][ct]);
        }
        if (t < 17) {
            #pragma unroll
            for (int ct = 0; ct < 4; ++ct) bcur[ct] = bnxt[ct];
        }
        if (ks == 5) {
            #pragma unroll
            for (int ct = 0; ct < 4; ++ct) {
                const int g0 = nc * 64 + ct * 16;
                const float4 bvf = *(const float4*)(bvec + g0 + l16 * 4);
                #pragma unroll
                for (int it = 0; it < 2; ++it) {
                    f32x4 s;
                    #pragma unroll
                    for (int r = 0; r < 4; ++r)
                        s[r] = acc[it][ct][r] + ((const float*)&bvf)[r];
                    *(f32x4*)(out + (size_t)orow[it] + g0 + l16 * 4) = s;
                }
            }
        }
    }
}

// ---------------------------------------------------------------------------
extern "C" void kernel_launch(void* const* d_in, const int* in_sizes, int n_in,
                              void* d_out, int out_size, void* d_ws, size_t ws_size,
                              hipStream_t stream)
{
    (void)in_sizes; (void)n_in; (void)out_size; (void)ws_size;
    const float* x      = (const float*)d_in[0];
    const float* mask   = (const float*)d_in[1];
    const float* qkv_w  = (const float*)d_in[2];
    const float* qkv_b  = (const float*)d_in[3];
    const float* proj_w = (const float*)d_in[4];
    const float* proj_b = (const float*)d_in[5];
    const float* rpb    = (const float*)d_in[6];
    const int*   rel    = (const int*)d_in[7];
    float* out = (float*)d_out;

    char* ws = (char*)d_ws;
    bf16* qb = (bf16*)ws;
    bf16* kb = qb + QKV_ELEMS;
    bf16* vb = kb + QKV_ELEMS;
    size_t off = 3 * QKV_ELEMS * sizeof(bf16);
    float* bias = (float*)(ws + off);
    off += ((size_t)NHEAD * NN * 4 + 255) / 256 * 256;
    bf16* ao = (bf16*)(ws + off);
    // overlapped weight buffers:
    bf16* qwb = ao;            // live only until qkv_gemm; attn rewrites ao after
    bf16* pwb = qb;            // written after attn (qb dead), read by proj

    build_bias<<<(NN + 255) / 256, 256, 0, stream>>>(rpb, rel, bias);
    wconv<<<(3 * CDIM * CDIM + 255) / 256, 256, 0, stream>>>(qkv_w, qwb, 3 * CDIM * CDIM);
    qkv_gemm<<<200704 / 64, 128, 0, stream>>>(x, qwb, qkv_b, qb, kb, vb);
    attn_fused<<<B_TOT, 448, 0, stream>>>(qb, kb, vb, mask, bias, ao);
    wconv<<<(CDIM * CDIM + 255) / 256, 256, 0, stream>>>(proj_w, pwb, CDIM * CDIM);
    proj_gemm<<<200704 / 64, 128, 0, stream>>>(ao, pwb, proj_b, out);
}

// Round 4
// 490.321 us; speedup vs baseline: 1.3857x; 1.1525x over previous
//
#include <hip/hip_runtime.h>
#include <hip/hip_bf16.h>

using bf16   = __bf16;
using bf16x4 = __attribute__((ext_vector_type(4))) __bf16;
using bf16x8 = __attribute__((ext_vector_type(8))) __bf16;
using f32x4  = __attribute__((ext_vector_type(4))) float;

#define B_TOT 2048
#define NTOK  98
#define CDIM  192
#define NHEAD 6
#define HDIM  32
#define NWIN  512
#define NN    (NTOK*NTOK)            /* 9604 */
#define QKV_ELEMS ((size_t)B_TOT*NHEAD*NTOK*HDIM)  /* 38535168 */
#define SCALE 0.17677669529663687f   /* 32^-0.5 */

#define MFMA(a,b,c) __builtin_amdgcn_mfma_f32_16x16x32_bf16((a),(b),(c),0,0,0)

// ---------------------------------------------------------------------------
// bias[h][i][j] = rpb_table[rel_pos_index[i*98+j]][h]
// ---------------------------------------------------------------------------
__global__ void build_bias(const float* __restrict__ table,
                           const int* __restrict__ rel,
                           float* __restrict__ bias) {
    int t = blockIdx.x * 256 + threadIdx.x;
    if (t < NN) {
        int idx = rel[t];
        #pragma unroll
        for (int h = 0; h < NHEAD; ++h)
            bias[h * NN + t] = table[idx * NHEAD + h];
    }
}

// f32 -> bf16 weight conversion (into dead ws regions)
__global__ void wconv(const float* __restrict__ w, bf16* __restrict__ wb, int n) {
    int t = blockIdx.x * 256 + threadIdx.x;
    if (t < n) wb[t] = (bf16)w[t];
}

// ---------------------------------------------------------------------------
// QKV GEMM v3 (unchanged from round 3). BM=64, 128 threads, A hoisted to
// regs, B-fragments double-buffered from global bf16 W, operands swapped.
// ---------------------------------------------------------------------------
__global__ __launch_bounds__(128, 3) void qkv_gemm(
    const float* __restrict__ x, const bf16* __restrict__ wb,
    const float* __restrict__ bvec,
    bf16* __restrict__ qdst, bf16* __restrict__ kdst, bf16* __restrict__ vdst)
{
    __shared__ char As[24576];   // 64 rows * 384 B (192 bf16), swizzled
    const int tid = threadIdx.x;
    const int m0  = blockIdx.x * 64;

    for (int c = tid; c < 64 * 48; c += 128) {
        int row = c / 48, c4 = c % 48;
        const float4 v = *(const float4*)(x + (size_t)(m0 + row) * CDIM + c4 * 4);
        bf16x4 p; p[0] = (bf16)v.x; p[1] = (bf16)v.y; p[2] = (bf16)v.z; p[3] = (bf16)v.w;
        *(bf16x4*)(As + row * 384 + ((((c4 >> 1) ^ (row & 7)) << 4) | ((c4 & 1) << 3))) = p;
    }
    __syncthreads();

    const int lane = tid & 63, wave = tid >> 6;
    const int l15 = lane & 15, l16 = lane >> 4;

    bf16x8 af[2][6];
    #pragma unroll
    for (int it = 0; it < 2; ++it) {
        int row = wave * 32 + it * 16 + l15;
        #pragma unroll
        for (int ks = 0; ks < 6; ++ks) {
            int kchunk = ks * 4 + l16;
            af[it][ks] = *(const bf16x8*)(As + row * 384 + ((kchunk ^ (row & 7)) << 4));
        }
    }

    int rowoff[2];
    #pragma unroll
    for (int it = 0; it < 2; ++it) {
        int row = m0 + wave * 32 + it * 16 + l15;
        rowoff[it] = (row / NTOK) * 18816 + (row % NTOK) * 32;
    }

    const bf16* wlane = wb + (size_t)l15 * CDIM + l16 * 8;

    const f32x4 z4 = {0.f, 0.f, 0.f, 0.f};
    f32x4 acc[2][4];
    bf16x8 bcur[4], bnxt[4];
    #pragma unroll
    for (int ct = 0; ct < 4; ++ct)
        bcur[ct] = *(const bf16x8*)(wlane + (size_t)(ct * 16) * CDIM);

    #pragma unroll
    for (int t = 0; t < 54; ++t) {
        const int nc = t / 6, ks = t % 6;
        if (ks == 0) {
            #pragma unroll
            for (int it = 0; it < 2; ++it)
                #pragma unroll
                for (int ct = 0; ct < 4; ++ct) acc[it][ct] = z4;
        }
        if (t < 53) {
            const int nn = (t + 1) / 6, kk = (t + 1) % 6;
            #pragma unroll
            for (int ct = 0; ct < 4; ++ct)
                bnxt[ct] = *(const bf16x8*)(wlane + (size_t)(nn * 64 + ct * 16) * CDIM + kk * 32);
        }
        #pragma unroll
        for (int ct = 0; ct < 4; ++ct) {
            acc[0][ct] = MFMA(bcur[ct], af[0][ks], acc[0][ct]);
            acc[1][ct] = MFMA(bcur[ct], af[1][ks], acc[1][ct]);
        }
        if (t < 53) {
            #pragma unroll
            for (int ct = 0; ct < 4; ++ct) bcur[ct] = bnxt[ct];
        }
        if (ks == 5) {
            #pragma unroll
            for (int ct = 0; ct < 4; ++ct) {
                const int g0    = nc * 64 + ct * 16;
                const int which = g0 / CDIM;
                const int cm    = g0 % CDIM;
                const int h     = cm >> 5, hd0 = cm & 31;
                const float4 bvf = *(const float4*)(bvec + g0 + l16 * 4);
                #pragma unroll
                for (int it = 0; it < 2; ++it) {
                    bf16x4 s;
                    #pragma unroll
                    for (int r = 0; r < 4; ++r) {
                        float v = acc[it][ct][r] + ((const float*)&bvf)[r];
                        if (which == 0) v *= SCALE;
                        s[r] = (bf16)v;
                    }
                    bf16* dp = (which == 0) ? qdst : (which == 1) ? kdst : vdst;
                    *(bf16x4*)(dp + rowoff[it] + h * 3136 + hd0 + l16 * 4) = s;
                }
            }
        }
    }
}

// ---------------------------------------------------------------------------
// Fused attention v4: one block per (window, head) — 12288 blocks, 7 waves.
// ONE barrier total (V staging); P is within-wave (own 16 rows). Deferred
// softmax normalization (1/s applied in PV epilogue via tiny LDS array).
// XCD-chunked block swizzle co-locates a window's 6 heads on one XCD L2.
// ---------------------------------------------------------------------------
__global__ __launch_bounds__(448) void attn_fused(
    const bf16* __restrict__ q, const bf16* __restrict__ k,
    const bf16* __restrict__ v,
    const float* __restrict__ mask, const float* __restrict__ bias,
    bf16* __restrict__ ao)
{
    __shared__ char lds[8192 + 28672 + 512];
    char* Vt = lds;           // 32 x 128 bf16, 256B rows, swizzled
    char* P  = lds + 8192;    // 112 x 128 bf16, 256B rows, swizzled
    float* invS = (float*)(lds + 8192 + 28672);   // 112 floats

    // XCD-chunked swizzle: 12288 blocks / 8 XCDs = 1536 per XCD; window's 6
    // heads land on consecutive work-ids -> same XCD.
    const int bid = blockIdx.x;
    const int bh  = (bid & 7) * 1536 + (bid >> 3);
    const int b = bh / NHEAD, h = bh % NHEAD;
    const int w = b & (NWIN - 1);
    const int tid = threadIdx.x, lane = tid & 63, it = tid >> 6;
    const int l15 = lane & 15, l16 = lane >> 4;

    // stage V^T into LDS (transpose; cols 98..127 zeroed below)
    const size_t bho = (size_t)bh * 3136;
    if (tid < 392) {
        int n = tid >> 2, hd0 = (tid & 3) * 8;
        bf16x8 vv = *(const bf16x8*)(v + bho + n * 32 + hd0);
        #pragma unroll
        for (int e = 0; e < 8; ++e) {
            int hd = hd0 + e;
            *(bf16*)(Vt + hd * 256 + (((n >> 3) ^ (hd & 7)) << 4) + ((n & 7) << 1)) = vv[e];
        }
    }
    for (int f = tid; f < 32 * 30; f += 448) {
        int hd = f / 30, n = 98 + f % 30;
        *(bf16*)(Vt + hd * 256 + (((n >> 3) ^ (hd & 7)) << 4) + ((n & 7) << 1)) = (bf16)0.f;
    }
    // zero own-wave P pad cols 112..127 (within-wave use only)
    {
        int zr = it * 16 + l15;
        int zc = 112 + l16 * 4;
        *(unsigned long long*)(P + zr * 256 + (((zc >> 3) ^ (zr & 7)) << 4) + ((zc & 7) << 1)) = 0ull;
    }

    // QK^T
    int qrow = it * 16 + l15; if (qrow > 97) qrow = 97;
    const bf16* qsrc = q + bho;
    const bf16* ksrc = k + bho;
    const bf16x8 qf = *(const bf16x8*)(qsrc + qrow * HDIM + l16 * 8);
    const f32x4 z4 = {0.f, 0.f, 0.f, 0.f};
    f32x4 acc[7];
    #pragma unroll
    for (int jt = 0; jt < 7; ++jt) {
        int kr = jt * 16 + l15; if (kr > 97) kr = 97;
        bf16x8 kf = *(const bf16x8*)(ksrc + kr * HDIM + l16 * 8);
        acc[jt] = MFMA(qf, kf, z4);
    }

    // bias + mask + softmax (deferred normalization)
    const float* mrow = mask + (size_t)w * NN;
    const float* brow = bias + (size_t)h * NN;
    #pragma unroll
    for (int r = 0; r < 4; ++r) {
        const int iact = it * 16 + l16 * 4 + r;          // actual row (may pad)
        int i = iact > 97 ? 97 : iact;                   // clamped for loads
        #pragma unroll
        for (int jt = 0; jt < 7; ++jt) {
            int j = jt * 16 + l15;
            acc[jt][r] = (j < NTOK)
                ? (acc[jt][r] + mrow[i * NTOK + j] + brow[i * NTOK + j])
                : -__builtin_inff();
        }
        float m = acc[0][r];
        #pragma unroll
        for (int jt = 1; jt < 7; ++jt) m = fmaxf(m, acc[jt][r]);
        m = fmaxf(m, __shfl_xor(m, 1, 16));
        m = fmaxf(m, __shfl_xor(m, 2, 16));
        m = fmaxf(m, __shfl_xor(m, 4, 16));
        m = fmaxf(m, __shfl_xor(m, 8, 16));
        float s = 0.f;
        #pragma unroll
        for (int jt = 0; jt < 7; ++jt) {
            float e = __expf(acc[jt][r] - m);
            acc[jt][r] = e; s += e;
        }
        s += __shfl_xor(s, 1, 16);
        s += __shfl_xor(s, 2, 16);
        s += __shfl_xor(s, 4, 16);
        s += __shfl_xor(s, 8, 16);
        if (l15 == 0) invS[iact] = 1.f / s;   // per-row reciprocal, applied in epilogue
    }

    // write unnormalized P (own wave's rows only — within-wave use)
    #pragma unroll
    for (int jt = 0; jt < 7; ++jt) {
        #pragma unroll
        for (int r = 0; r < 4; ++r) {
            int row = it * 16 + l16 * 4 + r;
            int j = jt * 16 + l15;
            *(bf16*)(P + row * 256 + (((j >> 3) ^ (row & 7)) << 4) + ((j & 7) << 1))
                = (bf16)acc[jt][r];
        }
    }
    __syncthreads();   // Vt staged by all waves (only barrier in the kernel)

    // PV (operand-swapped): lane holds row = it*16+l15, cols hd = l16*4+r (+16)
    f32x4 o0 = z4, o1 = z4;
    const int prow = it * 16 + l15;
    #pragma unroll
    for (int ks = 0; ks < 4; ++ks) {
        int kchunk = ks * 4 + l16;
        bf16x8 pf = *(const bf16x8*)(P + prow * 256 + ((kchunk ^ (prow & 7)) << 4));
        bf16x8 v0 = *(const bf16x8*)(Vt + l15 * 256 + ((kchunk ^ (l15 & 7)) << 4));
        bf16x8 v1 = *(const bf16x8*)(Vt + (16 + l15) * 256 + ((kchunk ^ (l15 & 7)) << 4));
        o0 = MFMA(v0, pf, o0);
        o1 = MFMA(v1, pf, o1);
    }

    {
        int row = it * 16 + l15;
        if (row < NTOK) {
            float inv = invS[row];
            bf16* dst = ao + (size_t)b * NTOK * CDIM + h * HDIM;
            bf16x4 s0, s1;
            #pragma unroll
            for (int r = 0; r < 4; ++r) {
                s0[r] = (bf16)(o0[r] * inv);
                s1[r] = (bf16)(o1[r] * inv);
            }
            *(bf16x4*)(dst + (size_t)row * CDIM + l16 * 4)      = s0;
            *(bf16x4*)(dst + (size_t)row * CDIM + 16 + l16 * 4) = s1;
        }
    }
}

// ---------------------------------------------------------------------------
// Proj GEMM v3 (unchanged from round 3).
// ---------------------------------------------------------------------------
__global__ __launch_bounds__(128, 3) void proj_gemm(
    const bf16* __restrict__ ao, const bf16* __restrict__ wb,
    const float* __restrict__ bvec, float* __restrict__ out)
{
    __shared__ char As[24576];
    const int tid = threadIdx.x;
    const int m0  = blockIdx.x * 64;

    for (int c = tid; c < 64 * 24; c += 128) {
        int row = c / 24, c8 = c % 24;
        bf16x8 vv = *(const bf16x8*)(ao + (size_t)(m0 + row) * CDIM + c8 * 8);
        *(bf16x8*)(As + row * 384 + ((c8 ^ (row & 7)) << 4)) = vv;
    }
    __syncthreads();

    const int lane = tid & 63, wave = tid >> 6;
    const int l15 = lane & 15, l16 = lane >> 4;

    bf16x8 af[2][6];
    #pragma unroll
    for (int it = 0; it < 2; ++it) {
        int row = wave * 32 + it * 16 + l15;
        #pragma unroll
        for (int ks = 0; ks < 6; ++ks) {
            int kchunk = ks * 4 + l16;
            af[it][ks] = *(const bf16x8*)(As + row * 384 + ((kchunk ^ (row & 7)) << 4));
        }
    }

    int orow[2];
    #pragma unroll
    for (int it = 0; it < 2; ++it)
        orow[it] = (m0 + wave * 32 + it * 16 + l15) * CDIM;

    const bf16* wlane = wb + (size_t)l15 * CDIM + l16 * 8;

    const f32x4 z4 = {0.f, 0.f, 0.f, 0.f};
    f32x4 acc[2][4];
    bf16x8 bcur[4], bnxt[4];
    #pragma unroll
    for (int ct = 0; ct < 4; ++ct)
        bcur[ct] = *(const bf16x8*)(wlane + (size_t)(ct * 16) * CDIM);

    #pragma unroll
    for (int t = 0; t < 18; ++t) {
        const int nc = t / 6, ks = t % 6;
        if (ks == 0) {
            #pragma unroll
            for (int it = 0; it < 2; ++it)
                #pragma unroll
                for (int ct = 0; ct < 4; ++ct) acc[it][ct] = z4;
        }
        if (t < 17) {
            const int nn = (t + 1) / 6, kk = (t + 1) % 6;
            #pragma unroll
            for (int ct = 0; ct < 4; ++ct)
                bnxt[ct] = *(const bf16x8*)(wlane + (size_t)(nn * 64 + ct * 16) * CDIM + kk * 32);
        }
        #pragma unroll
        for (int ct = 0; ct < 4; ++ct) {
            acc[0][ct] = MFMA(bcur[ct], af[0][ks], acc[0][ct]);
            acc[1][ct] = MFMA(bcur[ct], af[1][ks], acc[1][ct]);
        }
        if (t < 17) {
            #pragma unroll
            for (int ct = 0; ct < 4; ++ct) bcur[ct] = bnxt[ct];
        }
        if (ks == 5) {
            #pragma unroll
            for (int ct = 0; ct < 4; ++ct) {
                const int g0 = nc * 64 + ct * 16;
                const float4 bvf = *(const float4*)(bvec + g0 + l16 * 4);
                #pragma unroll
                for (int it = 0; it < 2; ++it) {
                    f32x4 s;
                    #pragma unroll
                    for (int r = 0; r < 4; ++r)
                        s[r] = acc[it][ct][r] + ((const float*)&bvf)[r];
                    *(f32x4*)(out + (size_t)orow[it] + g0 + l16 * 4) = s;
                }
            }
        }
    }
}

// ---------------------------------------------------------------------------
extern "C" void kernel_launch(void* const* d_in, const int* in_sizes, int n_in,
                              void* d_out, int out_size, void* d_ws, size_t ws_size,
                              hipStream_t stream)
{
    (void)in_sizes; (void)n_in; (void)out_size; (void)ws_size;
    const float* x      = (const float*)d_in[0];
    const float* mask   = (const float*)d_in[1];
    const float* qkv_w  = (const float*)d_in[2];
    const float* qkv_b  = (const float*)d_in[3];
    const float* proj_w = (const float*)d_in[4];
    const float* proj_b = (const float*)d_in[5];
    const float* rpb    = (const float*)d_in[6];
    const int*   rel    = (const int*)d_in[7];
    float* out = (float*)d_out;

    char* ws = (char*)d_ws;
    bf16* qb = (bf16*)ws;
    bf16* kb = qb + QKV_ELEMS;
    bf16* vb = kb + QKV_ELEMS;
    size_t off = 3 * QKV_ELEMS * sizeof(bf16);
    float* bias = (float*)(ws + off);
    off += ((size_t)NHEAD * NN * 4 + 255) / 256 * 256;
    bf16* ao = (bf16*)(ws + off);
    // overlapped weight buffers:
    bf16* qwb = ao;            // live only until qkv_gemm; attn rewrites ao after
    bf16* pwb = qb;            // written after attn (qb dead), read by proj

    build_bias<<<(NN + 255) / 256, 256, 0, stream>>>(rpb, rel, bias);
    wconv<<<(3 * CDIM * CDIM + 255) / 256, 256, 0, stream>>>(qkv_w, qwb, 3 * CDIM * CDIM);
    qkv_gemm<<<200704 / 64, 128, 0, stream>>>(x, qwb, qkv_b, qb, kb, vb);
    attn_fused<<<B_TOT * NHEAD, 448, 0, stream>>>(qb, kb, vb, mask, bias, ao);
    wconv<<<(CDIM * CDIM + 255) / 256, 256, 0, stream>>>(proj_w, pwb, CDIM * CDIM);
    proj_gemm<<<200704 / 64, 128, 0, stream>>>(ao, pwb, proj_b, out);
}

// Round 5
// 479.091 us; speedup vs baseline: 1.4182x; 1.0234x over previous
//
#include <hip/hip_runtime.h>
#include <hip/hip_bf16.h>

using bf16   = __bf16;
using bf16x4 = __attribute__((ext_vector_type(4))) __bf16;
using bf16x8 = __attribute__((ext_vector_type(8))) __bf16;
using f32x4  = __attribute__((ext_vector_type(4))) float;

#define B_TOT 2048
#define NTOK  98
#define CDIM  192
#define NHEAD 6
#define HDIM  32
#define NWIN  512
#define NN    (NTOK*NTOK)            /* 9604 */
#define QKV_ELEMS ((size_t)B_TOT*NHEAD*NTOK*HDIM)  /* 38535168 */
#define SCALE 0.17677669529663687f   /* 32^-0.5 */

#define MFMA(a,b,c) __builtin_amdgcn_mfma_f32_16x16x32_bf16((a),(b),(c),0,0,0)

// ---------------------------------------------------------------------------
// bias[h][i][j] = rpb_table[rel_pos_index[i*98+j]][h]
// ---------------------------------------------------------------------------
__global__ void build_bias(const float* __restrict__ table,
                           const int* __restrict__ rel,
                           float* __restrict__ bias) {
    int t = blockIdx.x * 256 + threadIdx.x;
    if (t < NN) {
        int idx = rel[t];
        #pragma unroll
        for (int h = 0; h < NHEAD; ++h)
            bias[h * NN + t] = table[idx * NHEAD + h];
    }
}

// f32 -> bf16 weight conversion (into dead ws regions)
__global__ void wconv(const float* __restrict__ w, bf16* __restrict__ wb, int n) {
    int t = blockIdx.x * 256 + threadIdx.x;
    if (t < n) wb[t] = (bf16)w[t];
}

// ---------------------------------------------------------------------------
// QKV GEMM v5: one WAVE per block (64 threads), 64 rows per wave, NO LDS,
// NO barriers. A-fragments loaded straight from global x (f32->bf16 in regs,
// rows are wave-private). B streamed from bf16 W with depth-2 register
// prefetch (triple buffer): loads for steps t+1,t+2 in flight during step t's
// 16 MFMAs -> ~2x16 MFMA issue-cycles of latency cover per wave.
// ---------------------------------------------------------------------------
__global__ __launch_bounds__(64, 2) void qkv_gemm(
    const float* __restrict__ x, const bf16* __restrict__ wb,
    const float* __restrict__ bvec,
    bf16* __restrict__ qdst, bf16* __restrict__ kdst, bf16* __restrict__ vdst)
{
    const int lane = threadIdx.x;
    const int l15 = lane & 15, l16 = lane >> 4;
    const int m0  = blockIdx.x * 64;

    // A fragments: af[it][ks] = x[m0+it*16+l15][ks*32+l16*8 .. +8] as bf16
    bf16x8 af[4][6];
    #pragma unroll
    for (int it = 0; it < 4; ++it) {
        const float* xr = x + (size_t)(m0 + it * 16 + l15) * CDIM + l16 * 8;
        #pragma unroll
        for (int ks = 0; ks < 6; ++ks) {
            float4 v0 = *(const float4*)(xr + ks * 32);
            float4 v1 = *(const float4*)(xr + ks * 32 + 4);
            bf16x8 a;
            a[0] = (bf16)v0.x; a[1] = (bf16)v0.y; a[2] = (bf16)v0.z; a[3] = (bf16)v0.w;
            a[4] = (bf16)v1.x; a[5] = (bf16)v1.y; a[6] = (bf16)v1.z; a[7] = (bf16)v1.w;
            af[it][ks] = a;
        }
    }

    // output row offsets (lane holds output row = m0 + it*16 + l15)
    int rowoff[4];
    #pragma unroll
    for (int it = 0; it < 4; ++it) {
        int row = m0 + it * 16 + l15;
        rowoff[it] = (row / NTOK) * 18816 + (row % NTOK) * 32;
    }

    const bf16* wlane = wb + (size_t)l15 * CDIM + l16 * 8;

    const f32x4 z4 = {0.f, 0.f, 0.f, 0.f};
    f32x4 acc[4][4];
    bf16x8 bbuf[3][4];   // statically indexed after full unroll

    // preload steps 0 (nc=0,ks=0) and 1 (nc=0,ks=1)
    #pragma unroll
    for (int ct = 0; ct < 4; ++ct) {
        bbuf[0][ct] = *(const bf16x8*)(wlane + (size_t)(ct * 16) * CDIM);
        bbuf[1][ct] = *(const bf16x8*)(wlane + (size_t)(ct * 16) * CDIM + 32);
    }

    #pragma unroll
    for (int t = 0; t < 54; ++t) {
        const int nc = t / 6, ks = t % 6;
        if (ks == 0) {
            #pragma unroll
            for (int it = 0; it < 4; ++it)
                #pragma unroll
                for (int ct = 0; ct < 4; ++ct) acc[it][ct] = z4;
        }
        if (t < 52) {   // prefetch step t+2
            const int tn = t + 2, nn = tn / 6, kk = tn % 6;
            #pragma unroll
            for (int ct = 0; ct < 4; ++ct)
                bbuf[tn % 3][ct] =
                    *(const bf16x8*)(wlane + (size_t)(nn * 64 + ct * 16) * CDIM + kk * 32);
        }
        #pragma unroll
        for (int ct = 0; ct < 4; ++ct) {
            #pragma unroll
            for (int it = 0; it < 4; ++it)
                acc[it][ct] = MFMA(bbuf[t % 3][ct], af[it][ks], acc[it][ct]);
        }
        if (ks == 5) {   // epilogue for chunk nc (which is constant per chunk)
            #pragma unroll
            for (int ct = 0; ct < 4; ++ct) {
                const int g0    = nc * 64 + ct * 16;
                const int which = g0 / CDIM;
                const int cm    = g0 % CDIM;
                const int h     = cm >> 5, hd0 = cm & 31;
                const float4 bvf = *(const float4*)(bvec + g0 + l16 * 4);
                #pragma unroll
                for (int it = 0; it < 4; ++it) {
                    bf16x4 s;
                    #pragma unroll
                    for (int r = 0; r < 4; ++r) {
                        float v = acc[it][ct][r] + ((const float*)&bvf)[r];
                        if (which == 0) v *= SCALE;
                        s[r] = (bf16)v;
                    }
                    bf16* dp = (which == 0) ? qdst : (which == 1) ? kdst : vdst;
                    *(bf16x4*)(dp + rowoff[it] + h * 3136 + hd0 + l16 * 4) = s;
                }
            }
        }
    }
}

// ---------------------------------------------------------------------------
// Fused attention v4 (unchanged from round 4): one block per (window, head),
// 7 waves, one barrier, deferred softmax normalization, XCD-chunked swizzle.
// ---------------------------------------------------------------------------
__global__ __launch_bounds__(448) void attn_fused(
    const bf16* __restrict__ q, const bf16* __restrict__ k,
    const bf16* __restrict__ v,
    const float* __restrict__ mask, const float* __restrict__ bias,
    bf16* __restrict__ ao)
{
    __shared__ char lds[8192 + 28672 + 512];
    char* Vt = lds;           // 32 x 128 bf16, 256B rows, swizzled
    char* P  = lds + 8192;    // 112 x 128 bf16, 256B rows, swizzled
    float* invS = (float*)(lds + 8192 + 28672);   // 112 floats

    const int bid = blockIdx.x;
    const int bh  = (bid & 7) * 1536 + (bid >> 3);
    const int b = bh / NHEAD, h = bh % NHEAD;
    const int w = b & (NWIN - 1);
    const int tid = threadIdx.x, lane = tid & 63, it = tid >> 6;
    const int l15 = lane & 15, l16 = lane >> 4;

    const size_t bho = (size_t)bh * 3136;
    if (tid < 392) {
        int n = tid >> 2, hd0 = (tid & 3) * 8;
        bf16x8 vv = *(const bf16x8*)(v + bho + n * 32 + hd0);
        #pragma unroll
        for (int e = 0; e < 8; ++e) {
            int hd = hd0 + e;
            *(bf16*)(Vt + hd * 256 + (((n >> 3) ^ (hd & 7)) << 4) + ((n & 7) << 1)) = vv[e];
        }
    }
    for (int f = tid; f < 32 * 30; f += 448) {
        int hd = f / 30, n = 98 + f % 30;
        *(bf16*)(Vt + hd * 256 + (((n >> 3) ^ (hd & 7)) << 4) + ((n & 7) << 1)) = (bf16)0.f;
    }
    {
        int zr = it * 16 + l15;
        int zc = 112 + l16 * 4;
        *(unsigned long long*)(P + zr * 256 + (((zc >> 3) ^ (zr & 7)) << 4) + ((zc & 7) << 1)) = 0ull;
    }

    int qrow = it * 16 + l15; if (qrow > 97) qrow = 97;
    const bf16* qsrc = q + bho;
    const bf16* ksrc = k + bho;
    const bf16x8 qf = *(const bf16x8*)(qsrc + qrow * HDIM + l16 * 8);
    const f32x4 z4 = {0.f, 0.f, 0.f, 0.f};
    f32x4 acc[7];
    #pragma unroll
    for (int jt = 0; jt < 7; ++jt) {
        int kr = jt * 16 + l15; if (kr > 97) kr = 97;
        bf16x8 kf = *(const bf16x8*)(ksrc + kr * HDIM + l16 * 8);
        acc[jt] = MFMA(qf, kf, z4);
    }

    const float* mrow = mask + (size_t)w * NN;
    const float* brow = bias + (size_t)h * NN;
    #pragma unroll
    for (int r = 0; r < 4; ++r) {
        const int iact = it * 16 + l16 * 4 + r;
        int i = iact > 97 ? 97 : iact;
        #pragma unroll
        for (int jt = 0; jt < 7; ++jt) {
            int j = jt * 16 + l15;
            acc[jt][r] = (j < NTOK)
                ? (acc[jt][r] + mrow[i * NTOK + j] + brow[i * NTOK + j])
                : -__builtin_inff();
        }
        float m = acc[0][r];
        #pragma unroll
        for (int jt = 1; jt < 7; ++jt) m = fmaxf(m, acc[jt][r]);
        m = fmaxf(m, __shfl_xor(m, 1, 16));
        m = fmaxf(m, __shfl_xor(m, 2, 16));
        m = fmaxf(m, __shfl_xor(m, 4, 16));
        m = fmaxf(m, __shfl_xor(m, 8, 16));
        float s = 0.f;
        #pragma unroll
        for (int jt = 0; jt < 7; ++jt) {
            float e = __expf(acc[jt][r] - m);
            acc[jt][r] = e; s += e;
        }
        s += __shfl_xor(s, 1, 16);
        s += __shfl_xor(s, 2, 16);
        s += __shfl_xor(s, 4, 16);
        s += __shfl_xor(s, 8, 16);
        if (l15 == 0) invS[iact] = 1.f / s;
    }

    #pragma unroll
    for (int jt = 0; jt < 7; ++jt) {
        #pragma unroll
        for (int r = 0; r < 4; ++r) {
            int row = it * 16 + l16 * 4 + r;
            int j = jt * 16 + l15;
            *(bf16*)(P + row * 256 + (((j >> 3) ^ (row & 7)) << 4) + ((j & 7) << 1))
                = (bf16)acc[jt][r];
        }
    }
    __syncthreads();

    f32x4 o0 = z4, o1 = z4;
    const int prow = it * 16 + l15;
    #pragma unroll
    for (int ks = 0; ks < 4; ++ks) {
        int kchunk = ks * 4 + l16;
        bf16x8 pf = *(const bf16x8*)(P + prow * 256 + ((kchunk ^ (prow & 7)) << 4));
        bf16x8 v0 = *(const bf16x8*)(Vt + l15 * 256 + ((kchunk ^ (l15 & 7)) << 4));
        bf16x8 v1 = *(const bf16x8*)(Vt + (16 + l15) * 256 + ((kchunk ^ (l15 & 7)) << 4));
        o0 = MFMA(v0, pf, o0);
        o1 = MFMA(v1, pf, o1);
    }

    {
        int row = it * 16 + l15;
        if (row < NTOK) {
            float inv = invS[row];
            bf16* dst = ao + (size_t)b * NTOK * CDIM + h * HDIM;
            bf16x4 s0, s1;
            #pragma unroll
            for (int r = 0; r < 4; ++r) {
                s0[r] = (bf16)(o0[r] * inv);
                s1[r] = (bf16)(o1[r] * inv);
            }
            *(bf16x4*)(dst + (size_t)row * CDIM + l16 * 4)      = s0;
            *(bf16x4*)(dst + (size_t)row * CDIM + 16 + l16 * 4) = s1;
        }
    }
}

// ---------------------------------------------------------------------------
// Proj GEMM v5: same no-LDS 1-wave structure as qkv v5 (A is already bf16).
// ---------------------------------------------------------------------------
__global__ __launch_bounds__(64, 2) void proj_gemm(
    const bf16* __restrict__ ao, const bf16* __restrict__ wb,
    const float* __restrict__ bvec, float* __restrict__ out)
{
    const int lane = threadIdx.x;
    const int l15 = lane & 15, l16 = lane >> 4;
    const int m0  = blockIdx.x * 64;

    bf16x8 af[4][6];
    #pragma unroll
    for (int it = 0; it < 4; ++it) {
        const bf16* ar = ao + (size_t)(m0 + it * 16 + l15) * CDIM + l16 * 8;
        #pragma unroll
        for (int ks = 0; ks < 6; ++ks)
            af[it][ks] = *(const bf16x8*)(ar + ks * 32);
    }

    int rowoff[4];
    #pragma unroll
    for (int it = 0; it < 4; ++it)
        rowoff[it] = (m0 + it * 16 + l15) * CDIM;

    const bf16* wlane = wb + (size_t)l15 * CDIM + l16 * 8;

    const f32x4 z4 = {0.f, 0.f, 0.f, 0.f};
    f32x4 acc[4][4];
    bf16x8 bbuf[3][4];

    #pragma unroll
    for (int ct = 0; ct < 4; ++ct) {
        bbuf[0][ct] = *(const bf16x8*)(wlane + (size_t)(ct * 16) * CDIM);
        bbuf[1][ct] = *(const bf16x8*)(wlane + (size_t)(ct * 16) * CDIM + 32);
    }

    #pragma unroll
    for (int t = 0; t < 18; ++t) {
        const int nc = t / 6, ks = t % 6;
        if (ks == 0) {
            #pragma unroll
            for (int it = 0; it < 4; ++it)
                #pragma unroll
                for (int ct = 0; ct < 4; ++ct) acc[it][ct] = z4;
        }
        if (t < 16) {
            const int tn = t + 2, nn = tn / 6, kk = tn % 6;
            #pragma unroll
            for (int ct = 0; ct < 4; ++ct)
                bbuf[tn % 3][ct] =
                    *(const bf16x8*)(wlane + (size_t)(nn * 64 + ct * 16) * CDIM + kk * 32);
        }
        #pragma unroll
        for (int ct = 0; ct < 4; ++ct) {
            #pragma unroll
            for (int it = 0; it < 4; ++it)
                acc[it][ct] = MFMA(bbuf[t % 3][ct], af[it][ks], acc[it][ct]);
        }
        if (ks == 5) {
            #pragma unroll
            for (int ct = 0; ct < 4; ++ct) {
                const int g0 = nc * 64 + ct * 16;
                const float4 bvf = *(const float4*)(bvec + g0 + l16 * 4);
                #pragma unroll
                for (int it = 0; it < 4; ++it) {
                    f32x4 s;
                    #pragma unroll
                    for (int r = 0; r < 4; ++r)
                        s[r] = acc[it][ct][r] + ((const float*)&bvf)[r];
                    *(f32x4*)(out + (size_t)rowoff[it] + g0 + l16 * 4) = s;
                }
            }
        }
    }
}

// ---------------------------------------------------------------------------
extern "C" void kernel_launch(void* const* d_in, const int* in_sizes, int n_in,
                              void* d_out, int out_size, void* d_ws, size_t ws_size,
                              hipStream_t stream)
{
    (void)in_sizes; (void)n_in; (void)out_size; (void)ws_size;
    const float* x      = (const float*)d_in[0];
    const float* mask   = (const float*)d_in[1];
    const float* qkv_w  = (const float*)d_in[2];
    const float* qkv_b  = (const float*)d_in[3];
    const float* proj_w = (const float*)d_in[4];
    const float* proj_b = (const float*)d_in[5];
    const float* rpb    = (const float*)d_in[6];
    const int*   rel    = (const int*)d_in[7];
    float* out = (float*)d_out;

    char* ws = (char*)d_ws;
    bf16* qb = (bf16*)ws;
    bf16* kb = qb + QKV_ELEMS;
    bf16* vb = kb + QKV_ELEMS;
    size_t off = 3 * QKV_ELEMS * sizeof(bf16);
    float* bias = (float*)(ws + off);
    off += ((size_t)NHEAD * NN * 4 + 255) / 256 * 256;
    bf16* ao = (bf16*)(ws + off);
    // overlapped weight buffers:
    bf16* qwb = ao;            // live only until qkv_gemm; attn rewrites ao after
    bf16* pwb = qb;            // written after attn (qb dead), read by proj

    build_bias<<<(NN + 255) / 256, 256, 0, stream>>>(rpb, rel, bias);
    wconv<<<(3 * CDIM * CDIM + 255) / 256, 256, 0, stream>>>(qkv_w, qwb, 3 * CDIM * CDIM);
    qkv_gemm<<<200704 / 64, 64, 0, stream>>>(x, qwb, qkv_b, qb, kb, vb);
    attn_fused<<<B_TOT * NHEAD, 448, 0, stream>>>(qb, kb, vb, mask, bias, ao);
    wconv<<<(CDIM * CDIM + 255) / 256, 256, 0, stream>>>(proj_w, pwb, CDIM * CDIM);
    proj_gemm<<<200704 / 64, 64, 0, stream>>>(ao, pwb, proj_b, out);
}